// Round 13
// baseline (2148.803 us; speedup 1.0000x reference)
//
#include <hip/hip_runtime.h>
#include <hip/hip_fp16.h>
#include <cstdint>
#include <cstddef>

#define NN 50000
#define EE 800000
#define NNZ (NN + EE)
#define KK 20
#define TPK 30
#define P1B 64
#define P1CH ((NN + P1B - 1) / P1B)  // 782
#define P1D 13                       // ceil(P1CH/64): max candidates a lane ingests
#define SCB 256
#define SCNB ((NN + SCB - 1) / SCB)  // 196

// ---------------- fp16 helpers ----------------

__device__ __forceinline__ float2 h2f(unsigned int u) {
  __half2 h = *reinterpret_cast<__half2*>(&u);
  return __half22float2(h);
}
__device__ __forceinline__ unsigned int f2h(float a, float b) {
  __half2 h = __floats2half2_rn(a, b);
  return *reinterpret_cast<unsigned int*>(&h);
}
__device__ __forceinline__ float wgt_of(unsigned int m) {  // high 16 bits = fp16 weight
  __half_raw hr;
  hr.x = (unsigned short)(m >> 16);
  return __half2float(__half(hr));
}

// ---------------- preprocessing ----------------

__global__ __launch_bounds__(256) void init_deg(int* deg) {
  int t = blockIdx.x * 256 + threadIdx.x;
  if (t < NN) deg[t] = 1;  // self-loop
}

__global__ __launch_bounds__(256) void count_deg(const int* __restrict__ ecol, int* deg) {
  int t = blockIdx.x * 256 + threadIdx.x;
  if (t < EE) atomicAdd(&deg[ecol[t]], 1);
}

__global__ __launch_bounds__(256) void scan_bsum(const int* __restrict__ deg, int* __restrict__ bsum) {
  __shared__ int red[256];
  int tid = threadIdx.x;
  int t = blockIdx.x * 256 + tid;
  red[tid] = (t < NN) ? deg[t] : 0;
  __syncthreads();
  for (int o = 128; o > 0; o >>= 1) {
    if (tid < o) red[tid] += red[tid + o];
    __syncthreads();
  }
  if (tid == 0) bsum[blockIdx.x] = red[0];
}

__global__ __launch_bounds__(256) void scan_boff(const int* __restrict__ bsum, int* __restrict__ boff) {
  __shared__ int s[256];
  int tid = threadIdx.x;
  int own = (tid < SCNB) ? bsum[tid] : 0;
  s[tid] = own;
  __syncthreads();
  for (int o = 1; o < 256; o <<= 1) {
    int v = s[tid];
    int u = (tid >= o) ? s[tid - o] : 0;
    __syncthreads();
    s[tid] = v + u;
    __syncthreads();
  }
  if (tid < SCNB) boff[tid] = s[tid] - own;  // exclusive
}

__global__ __launch_bounds__(256) void scan_write(const int* __restrict__ deg,
                                                  const int* __restrict__ boff,
                                                  int* __restrict__ rowptr, int* __restrict__ cursor,
                                                  float* __restrict__ dinv) {
  __shared__ int s[256];
  int tid = threadIdx.x;
  int t = blockIdx.x * 256 + tid;
  int d = (t < NN) ? deg[t] : 0;
  s[tid] = d;
  __syncthreads();
  for (int o = 1; o < 256; o <<= 1) {
    int v = s[tid];
    int u = (tid >= o) ? s[tid - o] : 0;
    __syncthreads();
    s[tid] = v + u;
    __syncthreads();
  }
  if (t < NN) {
    int excl = boff[blockIdx.x] + s[tid] - d;
    rowptr[t] = excl;
    cursor[t] = excl;
    dinv[t] = 1.0f / sqrtf((float)d);
    if (t == NN - 1) rowptr[NN] = excl + d;
  }
}

// meta4: packed edge record = (fp16 weight << 16) | src  (src < 65536 since NN=50000)
__global__ __launch_bounds__(256) void scatter_csr(const int* __restrict__ erow,
                                                   const int* __restrict__ ecol,
                                                   const float* __restrict__ dinv, int* cursor,
                                                   unsigned int* __restrict__ meta4) {
  int t = blockIdx.x * 256 + threadIdx.x;
  if (t < EE) {
    int r = erow[t], c = ecol[t];
    int p = atomicAdd(&cursor[c], 1);
    __half_raw hr = __half_raw(__float2half_rn(dinv[r] * dinv[c]));
    meta4[p] = ((unsigned int)hr.x << 16) | (unsigned int)r;
  } else if (t < NNZ) {
    int i = t - EE;
    int p = atomicAdd(&cursor[i], 1);
    __half_raw hr = __half_raw(__float2half_rn(dinv[i] * dinv[i]));
    meta4[p] = ((unsigned int)hr.x << 16) | (unsigned int)i;
  }
}

// writes f32 x0 (float4 rows) AND fp16 x0 (uint2 rows)
__global__ __launch_bounds__(256) void extract_x0(const float* __restrict__ x,
                                                  float4* __restrict__ x0f,
                                                  uint2* __restrict__ x0h) {
  int t = blockIdx.x * 256 + threadIdx.x;
  if (t < NN) {
    float4 v = *(const float4*)&x[(size_t)t * 8];
    x0f[t] = v;
    uint2 h;
    h.x = f2h(v.x, v.y);
    h.y = f2h(v.z, v.w);
    x0h[t] = h;
  }
}

// ---------------- propagation sweeps ----------------
// tout[v] = aacc * sum_e nrm[e]*tin[src[e]] + axc * xin[v]

// 64-channel fp16 sweep, TWO nodes per wave, trip-unrolled x2:
// FOUR independent 128B row-gathers in flight per wave.
// meta4 packed: one __shfl per edge. Lane = (e8 edge-slot, c8 channel-group).
// All trip counts wave-uniform; lanes >= nj hold m=0 (weight 0).
// Epilogue x-row loads are issued BEFORE the gather loop (predicated e8==0)
// so their latency hides under the gathers.
__global__ __launch_bounds__(256) void sweep64h(const uint4* __restrict__ tinq,
                                                const uint4* __restrict__ xinq,
                                                const float4* __restrict__ xinf,
                                                uint4* __restrict__ touth,
                                                float4* __restrict__ toutf,
                                                const int* __restrict__ rowptr,
                                                const unsigned int* __restrict__ meta4,
                                                float aacc, float axc, int isFinal) {
  int lane = threadIdx.x & 63;
  int w = threadIdx.x >> 6;
  int v0 = (blockIdx.x * 4 + w) * 2;  // grid exact: (NN/8) blocks, NN even
  int v1 = v0 + 1;
  if (v0 >= NN) return;
  int c8 = lane & 7;
  int e8 = lane >> 3;
  int s0 = rowptr[v0];
  int s1 = rowptr[v0 + 1];
  int e1 = rowptr[v0 + 2];
  int d0 = s1 - s0, d1 = e1 - s1;
  int nj0 = (d0 > 64) ? 64 : d0;
  int nj1 = (d1 > 64) ? 64 : d1;
  unsigned int mA = (lane < nj0) ? meta4[s0 + lane] : 0u;
  unsigned int mB = (lane < nj1) ? meta4[s1 + lane] : 0u;
  // prefetch epilogue x rows (only e8==0 lanes participate in the epilogue)
  uint4 xq0 = make_uint4(0, 0, 0, 0), xq1 = make_uint4(0, 0, 0, 0);
  float4 xf00, xf01, xf10, xf11;
  if (!isFinal) {
    if (e8 == 0) {
      xq0 = xinq[(size_t)v0 * 8 + c8];
      xq1 = xinq[(size_t)v1 * 8 + c8];
    }
  } else {
    if (e8 == 0) {
      xf00 = xinf[(size_t)v0 * 16 + c8 * 2];
      xf01 = xinf[(size_t)v0 * 16 + c8 * 2 + 1];
      xf10 = xinf[(size_t)v1 * 16 + c8 * 2];
      xf11 = xinf[(size_t)v1 * 16 + c8 * 2 + 1];
    }
  }
  float a0 = 0.f, a1 = 0.f, a2 = 0.f, a3 = 0.f;
  float a4 = 0.f, a5 = 0.f, a6 = 0.f, a7 = 0.f;
  float b0 = 0.f, b1 = 0.f, b2 = 0.f, b3 = 0.f;
  float b4 = 0.f, b5 = 0.f, b6 = 0.f, b7 = 0.f;
  int T0 = (nj0 + 7) >> 3;
  int T1 = (nj1 + 7) >> 3;
  int Tc = (T0 < T1) ? T0 : T1;
  int t = 0;
  for (; t + 1 < Tc; t += 2) {  // 4 gathers in flight
    int j0 = e8 + 8 * t;
    int j1 = j0 + 8;
    unsigned int ma0 = __shfl(mA, j0);
    unsigned int mb0 = __shfl(mB, j0);
    unsigned int ma1 = __shfl(mA, j1);
    unsigned int mb1 = __shfl(mB, j1);
    uint4 qa0 = tinq[(size_t)(ma0 & 0xffffu) * 8 + c8];
    uint4 qb0 = tinq[(size_t)(mb0 & 0xffffu) * 8 + c8];
    uint4 qa1 = tinq[(size_t)(ma1 & 0xffffu) * 8 + c8];
    uint4 qb1 = tinq[(size_t)(mb1 & 0xffffu) * 8 + c8];
    float wa0 = wgt_of(ma0), wb0 = wgt_of(mb0);
    float wa1 = wgt_of(ma1), wb1 = wgt_of(mb1);
    float2 f;
    f = h2f(qa0.x); a0 = fmaf(wa0, f.x, a0); a1 = fmaf(wa0, f.y, a1);
    f = h2f(qa0.y); a2 = fmaf(wa0, f.x, a2); a3 = fmaf(wa0, f.y, a3);
    f = h2f(qa0.z); a4 = fmaf(wa0, f.x, a4); a5 = fmaf(wa0, f.y, a5);
    f = h2f(qa0.w); a6 = fmaf(wa0, f.x, a6); a7 = fmaf(wa0, f.y, a7);
    f = h2f(qb0.x); b0 = fmaf(wb0, f.x, b0); b1 = fmaf(wb0, f.y, b1);
    f = h2f(qb0.y); b2 = fmaf(wb0, f.x, b2); b3 = fmaf(wb0, f.y, b3);
    f = h2f(qb0.z); b4 = fmaf(wb0, f.x, b4); b5 = fmaf(wb0, f.y, b5);
    f = h2f(qb0.w); b6 = fmaf(wb0, f.x, b6); b7 = fmaf(wb0, f.y, b7);
    f = h2f(qa1.x); a0 = fmaf(wa1, f.x, a0); a1 = fmaf(wa1, f.y, a1);
    f = h2f(qa1.y); a2 = fmaf(wa1, f.x, a2); a3 = fmaf(wa1, f.y, a3);
    f = h2f(qa1.z); a4 = fmaf(wa1, f.x, a4); a5 = fmaf(wa1, f.y, a5);
    f = h2f(qa1.w); a6 = fmaf(wa1, f.x, a6); a7 = fmaf(wa1, f.y, a7);
    f = h2f(qb1.x); b0 = fmaf(wb1, f.x, b0); b1 = fmaf(wb1, f.y, b1);
    f = h2f(qb1.y); b2 = fmaf(wb1, f.x, b2); b3 = fmaf(wb1, f.y, b3);
    f = h2f(qb1.z); b4 = fmaf(wb1, f.x, b4); b5 = fmaf(wb1, f.y, b5);
    f = h2f(qb1.w); b6 = fmaf(wb1, f.x, b6); b7 = fmaf(wb1, f.y, b7);
  }
  for (; t < Tc; ++t) {  // odd-trip remainder: 2 gathers in flight
    int j = e8 + 8 * t;
    unsigned int ma = __shfl(mA, j);
    unsigned int mb = __shfl(mB, j);
    uint4 qa = tinq[(size_t)(ma & 0xffffu) * 8 + c8];
    uint4 qb = tinq[(size_t)(mb & 0xffffu) * 8 + c8];
    float wa = wgt_of(ma), wb = wgt_of(mb);
    float2 f;
    f = h2f(qa.x); a0 = fmaf(wa, f.x, a0); a1 = fmaf(wa, f.y, a1);
    f = h2f(qa.y); a2 = fmaf(wa, f.x, a2); a3 = fmaf(wa, f.y, a3);
    f = h2f(qa.z); a4 = fmaf(wa, f.x, a4); a5 = fmaf(wa, f.y, a5);
    f = h2f(qa.w); a6 = fmaf(wa, f.x, a6); a7 = fmaf(wa, f.y, a7);
    f = h2f(qb.x); b0 = fmaf(wb, f.x, b0); b1 = fmaf(wb, f.y, b1);
    f = h2f(qb.y); b2 = fmaf(wb, f.x, b2); b3 = fmaf(wb, f.y, b3);
    f = h2f(qb.z); b4 = fmaf(wb, f.x, b4); b5 = fmaf(wb, f.y, b5);
    f = h2f(qb.w); b6 = fmaf(wb, f.x, b6); b7 = fmaf(wb, f.y, b7);
  }
  for (; t < T0; ++t) {  // drain A
    int j = e8 + 8 * t;
    unsigned int ma = __shfl(mA, j);
    float wa = wgt_of(ma);
    uint4 qa = tinq[(size_t)(ma & 0xffffu) * 8 + c8];
    float2 f;
    f = h2f(qa.x); a0 = fmaf(wa, f.x, a0); a1 = fmaf(wa, f.y, a1);
    f = h2f(qa.y); a2 = fmaf(wa, f.x, a2); a3 = fmaf(wa, f.y, a3);
    f = h2f(qa.z); a4 = fmaf(wa, f.x, a4); a5 = fmaf(wa, f.y, a5);
    f = h2f(qa.w); a6 = fmaf(wa, f.x, a6); a7 = fmaf(wa, f.y, a7);
  }
  for (; t < T1; ++t) {  // drain B
    int j = e8 + 8 * t;
    unsigned int mb = __shfl(mB, j);
    float wb = wgt_of(mb);
    uint4 qb = tinq[(size_t)(mb & 0xffffu) * 8 + c8];
    float2 f;
    f = h2f(qb.x); b0 = fmaf(wb, f.x, b0); b1 = fmaf(wb, f.y, b1);
    f = h2f(qb.y); b2 = fmaf(wb, f.x, b2); b3 = fmaf(wb, f.y, b3);
    f = h2f(qb.z); b4 = fmaf(wb, f.x, b4); b5 = fmaf(wb, f.y, b5);
    f = h2f(qb.w); b6 = fmaf(wb, f.x, b6); b7 = fmaf(wb, f.y, b7);
  }
  // cold overflow path (deg > 64)
  if (d0 > 64) {
    int e = s0 + d0;
    for (int c2 = s0 + 64; c2 < e; c2 += 64) {
      int nj2 = e - c2; if (nj2 > 64) nj2 = 64;
      unsigned int mX = (lane < nj2) ? meta4[c2 + lane] : 0u;
      int T2 = (nj2 + 7) >> 3;
      for (int t2 = 0; t2 < T2; ++t2) {
        int j = e8 + 8 * t2;
        unsigned int ma = __shfl(mX, j);
        float wa = wgt_of(ma);
        uint4 qa = tinq[(size_t)(ma & 0xffffu) * 8 + c8];
        float2 f;
        f = h2f(qa.x); a0 = fmaf(wa, f.x, a0); a1 = fmaf(wa, f.y, a1);
        f = h2f(qa.y); a2 = fmaf(wa, f.x, a2); a3 = fmaf(wa, f.y, a3);
        f = h2f(qa.z); a4 = fmaf(wa, f.x, a4); a5 = fmaf(wa, f.y, a5);
        f = h2f(qa.w); a6 = fmaf(wa, f.x, a6); a7 = fmaf(wa, f.y, a7);
      }
    }
  }
  if (d1 > 64) {
    int e = s1 + d1;
    for (int c2 = s1 + 64; c2 < e; c2 += 64) {
      int nj2 = e - c2; if (nj2 > 64) nj2 = 64;
      unsigned int mX = (lane < nj2) ? meta4[c2 + lane] : 0u;
      int T2 = (nj2 + 7) >> 3;
      for (int t2 = 0; t2 < T2; ++t2) {
        int j = e8 + 8 * t2;
        unsigned int mb = __shfl(mX, j);
        float wb = wgt_of(mb);
        uint4 qb = tinq[(size_t)(mb & 0xffffu) * 8 + c8];
        float2 f;
        f = h2f(qb.x); b0 = fmaf(wb, f.x, b0); b1 = fmaf(wb, f.y, b1);
        f = h2f(qb.y); b2 = fmaf(wb, f.x, b2); b3 = fmaf(wb, f.y, b3);
        f = h2f(qb.z); b4 = fmaf(wb, f.x, b4); b5 = fmaf(wb, f.y, b5);
        f = h2f(qb.w); b6 = fmaf(wb, f.x, b6); b7 = fmaf(wb, f.y, b7);
      }
    }
  }
  // reduce across the 8 e-slots (lane bits 3..5), both nodes interleaved
#pragma unroll
  for (int o = 8; o <= 32; o <<= 1) {
    a0 += __shfl_xor(a0, o); b0 += __shfl_xor(b0, o);
    a1 += __shfl_xor(a1, o); b1 += __shfl_xor(b1, o);
    a2 += __shfl_xor(a2, o); b2 += __shfl_xor(b2, o);
    a3 += __shfl_xor(a3, o); b3 += __shfl_xor(b3, o);
    a4 += __shfl_xor(a4, o); b4 += __shfl_xor(b4, o);
    a5 += __shfl_xor(a5, o); b5 += __shfl_xor(b5, o);
    a6 += __shfl_xor(a6, o); b6 += __shfl_xor(b6, o);
    a7 += __shfl_xor(a7, o); b7 += __shfl_xor(b7, o);
  }
  if (e8 == 0) {
    if (!isFinal) {
      float2 f;
      uint4 r;
      f = h2f(xq0.x); r.x = f2h(a0 + f.x, a1 + f.y);
      f = h2f(xq0.y); r.y = f2h(a2 + f.x, a3 + f.y);
      f = h2f(xq0.z); r.z = f2h(a4 + f.x, a5 + f.y);
      f = h2f(xq0.w); r.w = f2h(a6 + f.x, a7 + f.y);
      touth[(size_t)v0 * 8 + c8] = r;
      f = h2f(xq1.x); r.x = f2h(b0 + f.x, b1 + f.y);
      f = h2f(xq1.y); r.y = f2h(b2 + f.x, b3 + f.y);
      f = h2f(xq1.z); r.z = f2h(b4 + f.x, b5 + f.y);
      f = h2f(xq1.w); r.w = f2h(b6 + f.x, b7 + f.y);
      touth[(size_t)v1 * 8 + c8] = r;
    } else {
      float4 r0, r1;
      r0.x = aacc * a0 + axc * xf00.x; r0.y = aacc * a1 + axc * xf00.y;
      r0.z = aacc * a2 + axc * xf00.z; r0.w = aacc * a3 + axc * xf00.w;
      r1.x = aacc * a4 + axc * xf01.x; r1.y = aacc * a5 + axc * xf01.y;
      r1.z = aacc * a6 + axc * xf01.z; r1.w = aacc * a7 + axc * xf01.w;
      toutf[(size_t)v0 * 16 + c8 * 2] = r0;
      toutf[(size_t)v0 * 16 + c8 * 2 + 1] = r1;
      r0.x = aacc * b0 + axc * xf10.x; r0.y = aacc * b1 + axc * xf10.y;
      r0.z = aacc * b2 + axc * xf10.z; r0.w = aacc * b3 + axc * xf10.w;
      r1.x = aacc * b4 + axc * xf11.x; r1.y = aacc * b5 + axc * xf11.y;
      r1.z = aacc * b6 + axc * xf11.z; r1.w = aacc * b7 + axc * xf11.w;
      toutf[(size_t)v1 * 16 + c8 * 2] = r0;
      toutf[(size_t)v1 * 16 + c8 * 2 + 1] = r1;
    }
  }
}

// 4-channel fp16 sweep: wave = 16 nodes x 4 edge slots; 8B fp16 rows (table
// 400 KB -> L2-resident on every XCD); unrolled x4; meta4 packed.
// Non-final writes fp16; final combines with f32 x0 and writes f32 for dense4.
__global__ __launch_bounds__(256) void sweep4h(const uint2* __restrict__ tin,
                                               const uint2* __restrict__ xinh,
                                               const float4* __restrict__ xinf,
                                               uint2* __restrict__ touth,
                                               float4* __restrict__ toutf,
                                               const int* __restrict__ rowptr,
                                               const unsigned int* __restrict__ meta4,
                                               float aacc, float axc, int isFinal) {
  int lane = threadIdx.x & 63;
  int w = threadIdx.x >> 6;
  int n16 = lane & 15;
  int e4 = lane >> 4;
  int v = (blockIdx.x * 4 + w) * 16 + n16;
  int vv = (v < NN) ? v : (NN - 1);
  int s = rowptr[vv], e = rowptr[vv + 1];
  float a0 = 0.f, a1 = 0.f, a2 = 0.f, a3 = 0.f;
  float b0 = 0.f, b1 = 0.f, b2 = 0.f, b3 = 0.f;
  int i = s + e4;
  for (; i + 12 < e; i += 16) {
    unsigned int m0 = meta4[i];
    unsigned int m1 = meta4[i + 4];
    unsigned int m2 = meta4[i + 8];
    unsigned int m3 = meta4[i + 12];
    uint2 q0 = tin[m0 & 0xffffu];
    uint2 q1 = tin[m1 & 0xffffu];
    uint2 q2 = tin[m2 & 0xffffu];
    uint2 q3 = tin[m3 & 0xffffu];
    float w0 = wgt_of(m0), w1 = wgt_of(m1), w2 = wgt_of(m2), w3 = wgt_of(m3);
    float2 f;
    f = h2f(q0.x); a0 = fmaf(w0, f.x, a0); a1 = fmaf(w0, f.y, a1);
    f = h2f(q0.y); a2 = fmaf(w0, f.x, a2); a3 = fmaf(w0, f.y, a3);
    f = h2f(q1.x); b0 = fmaf(w1, f.x, b0); b1 = fmaf(w1, f.y, b1);
    f = h2f(q1.y); b2 = fmaf(w1, f.x, b2); b3 = fmaf(w1, f.y, b3);
    f = h2f(q2.x); a0 = fmaf(w2, f.x, a0); a1 = fmaf(w2, f.y, a1);
    f = h2f(q2.y); a2 = fmaf(w2, f.x, a2); a3 = fmaf(w2, f.y, a3);
    f = h2f(q3.x); b0 = fmaf(w3, f.x, b0); b1 = fmaf(w3, f.y, b1);
    f = h2f(q3.y); b2 = fmaf(w3, f.x, b2); b3 = fmaf(w3, f.y, b3);
  }
  for (; i < e; i += 4) {
    unsigned int m0 = meta4[i];
    float w0 = wgt_of(m0);
    uint2 q0 = tin[m0 & 0xffffu];
    float2 f;
    f = h2f(q0.x); a0 = fmaf(w0, f.x, a0); a1 = fmaf(w0, f.y, a1);
    f = h2f(q0.y); a2 = fmaf(w0, f.x, a2); a3 = fmaf(w0, f.y, a3);
  }
  a0 += b0; a1 += b1; a2 += b2; a3 += b3;
  a0 += __shfl_xor(a0, 16); a1 += __shfl_xor(a1, 16);
  a2 += __shfl_xor(a2, 16); a3 += __shfl_xor(a3, 16);
  a0 += __shfl_xor(a0, 32); a1 += __shfl_xor(a1, 32);
  a2 += __shfl_xor(a2, 32); a3 += __shfl_xor(a3, 32);
  if (e4 == 0 && v < NN) {
    if (!isFinal) {
      uint2 xq = xinh[v];
      float2 f;
      uint2 r;
      f = h2f(xq.x); r.x = f2h(a0 + f.x, a1 + f.y);
      f = h2f(xq.y); r.y = f2h(a2 + f.x, a3 + f.y);
      touth[v] = r;
    } else {
      float4 xv = xinf[v];
      float4 o;
      o.x = aacc * a0 + axc * xv.x;
      o.y = aacc * a1 + axc * xv.y;
      o.z = aacc * a2 + axc * xv.z;
      o.w = aacc * a3 + axc * xv.w;
      toutf[v] = o;
    }
  }
}

// ---------------- dense layers ----------------

// emits f32 out AND fp16 copy for the next layer's propagation
__global__ __launch_bounds__(256) void dense4(const float* __restrict__ h4,
                                              const float* __restrict__ W,  // [64][4]
                                              const float* __restrict__ b,
                                              float* __restrict__ out,
                                              unsigned int* __restrict__ outh) {
  __shared__ float sWt[4 * 64];
  int tid = threadIdx.x;
  {
    int j = tid >> 2, c = tid & 3;
    sWt[c * 64 + j] = W[tid];
  }
  __syncthreads();
  int lane = tid & 63, w = tid >> 6;
  int n = blockIdx.x * 4 + w;
  if (n >= NN) return;  // wave-uniform
  float acc = b[lane];
#pragma unroll
  for (int c = 0; c < 4; ++c)
    acc = fmaf(h4[(size_t)n * 4 + c], sWt[c * 64 + lane], acc);
  acc = fmaxf(acc, 0.f);
  out[(size_t)n * 64 + lane] = acc;
  int p = lane & 31;
  float va = __shfl(acc, 2 * p);
  float vb = __shfl(acc, 2 * p + 1);
  if (lane < 32) outh[(size_t)n * 32 + lane] = f2h(va, vb);
}

// 128 nodes per block; thread = (node j, out-quarter q) covering nodes {j, j+64}
#define DN 128
__global__ __launch_bounds__(256) void dense64(const float* __restrict__ h,
                                               const float* __restrict__ W,  // [64][64]
                                               const float* __restrict__ b,
                                               const float* __restrict__ resid,
                                               float* __restrict__ out,
                                               uint4* __restrict__ outh,  // optional fp16 copy
                                               int doRelu, int doResid) {
  __shared__ float sX[64 * 130];
  __shared__ float sWt[64 * 68];
  int tid = threadIdx.x;
  int base = blockIdx.x * DN;
  for (int i = tid; i < 64 * 64; i += 256) {
    int o = i >> 6, c = i & 63;
    sWt[c * 68 + o] = W[i];
  }
  for (int i = tid; i < DN * 64; i += 256) {
    int node = i >> 6, c = i & 63;
    int n = base + node;
    sX[c * 130 + node] = (n < NN) ? h[(size_t)n * 64 + c] : 0.f;
  }
  __syncthreads();
  int j = tid & 63;
  int q = tid >> 6;
  float acc0[16], acc1[16];
#pragma unroll
  for (int o = 0; o < 16; ++o) { acc0[o] = b[q * 16 + o]; acc1[o] = acc0[o]; }
  for (int c = 0; c < 64; ++c) {
    float x0 = sX[c * 130 + j];
    float x1 = sX[c * 130 + 64 + j];
#pragma unroll
    for (int o4 = 0; o4 < 4; ++o4) {
      float4 wv = *(const float4*)&sWt[c * 68 + q * 16 + o4 * 4];
      acc0[o4 * 4 + 0] = fmaf(x0, wv.x, acc0[o4 * 4 + 0]);
      acc0[o4 * 4 + 1] = fmaf(x0, wv.y, acc0[o4 * 4 + 1]);
      acc0[o4 * 4 + 2] = fmaf(x0, wv.z, acc0[o4 * 4 + 2]);
      acc0[o4 * 4 + 3] = fmaf(x0, wv.w, acc0[o4 * 4 + 3]);
      acc1[o4 * 4 + 0] = fmaf(x1, wv.x, acc1[o4 * 4 + 0]);
      acc1[o4 * 4 + 1] = fmaf(x1, wv.y, acc1[o4 * 4 + 1]);
      acc1[o4 * 4 + 2] = fmaf(x1, wv.z, acc1[o4 * 4 + 2]);
      acc1[o4 * 4 + 3] = fmaf(x1, wv.w, acc1[o4 * 4 + 3]);
    }
  }
  int n0 = base + j, n1 = base + 64 + j;
#pragma unroll
  for (int half = 0; half < 2; ++half) {
    int n = half ? n1 : n0;
    float* acc = half ? acc1 : acc0;
    if (n < NN) {
      if (doRelu) {
#pragma unroll
        for (int o = 0; o < 16; ++o) acc[o] = fmaxf(acc[o], 0.f);
      }
      if (doResid) {
#pragma unroll
        for (int o4 = 0; o4 < 4; ++o4) {
          float4 rv = *(const float4*)&resid[(size_t)n * 64 + q * 16 + o4 * 4];
          acc[o4 * 4 + 0] += rv.x; acc[o4 * 4 + 1] += rv.y;
          acc[o4 * 4 + 2] += rv.z; acc[o4 * 4 + 3] += rv.w;
        }
      }
#pragma unroll
      for (int o4 = 0; o4 < 4; ++o4) {
        float4 r;
        r.x = acc[o4 * 4 + 0]; r.y = acc[o4 * 4 + 1];
        r.z = acc[o4 * 4 + 2]; r.w = acc[o4 * 4 + 3];
        *(float4*)&out[(size_t)n * 64 + q * 16 + o4 * 4] = r;
      }
      if (outh) {
        uint4 u;
        u.x = f2h(acc[0], acc[1]);  u.y = f2h(acc[2], acc[3]);
        u.z = f2h(acc[4], acc[5]);  u.w = f2h(acc[6], acc[7]);
        outh[(size_t)n * 8 + q * 2] = u;
        u.x = f2h(acc[8], acc[9]);  u.y = f2h(acc[10], acc[11]);
        u.z = f2h(acc[12], acc[13]); u.w = f2h(acc[14], acc[15]);
        outh[(size_t)n * 8 + q * 2 + 1] = u;
      }
    }
  }
}

// ---------------- scoring / selection / output ----------------

__global__ __launch_bounds__(256) void score_k(const float* __restrict__ y,
                                               const float* __restrict__ wp,
                                               float* __restrict__ scores) {
  int tid = threadIdx.x;
  int lane = tid & 63, w = tid >> 6;
  int n = blockIdx.x * 4 + w;
  if (n >= NN) return;
  float wv = wp[lane];
  float s = wv * wv;
#pragma unroll
  for (int o = 32; o > 0; o >>= 1) s += __shfl_xor(s, o);
  float invn = 1.0f / sqrtf(s);
  float p = y[(size_t)n * 64 + lane] * wv;
#pragma unroll
  for (int o = 32; o > 0; o >>= 1) p += __shfl_xor(p, o);
  if (lane == 0) scores[n] = tanhf(p * invn);
}

__device__ __forceinline__ bool lexgt(float v1, int i1, float v2, int i2) {
  return (v1 > v2) || (v1 == v2 && i1 < i2);
}

// phase 1: 64 single-wave blocks, each emits its chunk's SORTED top-30.
__global__ __launch_bounds__(64, 1) void topk_p1(const float* __restrict__ score,
                                                 float* __restrict__ candv,
                                                 int* __restrict__ candi) {
  int lane = threadIdx.x;
  int base = blockIdx.x * P1CH;
  float lv[P1D]; int li[P1D];
#pragma unroll
  for (int k = 0; k < P1D; ++k) { lv[k] = -3.4e38f; li[k] = 0x7FFFFFFF; }
  for (int k = lane; k < P1CH; k += 64) {
    int idx = base + k;
    if (idx >= NN) break;
    float v = score[idx];
    if (lexgt(v, idx, lv[P1D - 1], li[P1D - 1])) {
      float cv = v; int ci = idx;
#pragma unroll
      for (int m = 0; m < P1D; ++m) {
        bool sw = lexgt(cv, ci, lv[m], li[m]);
        float tv = sw ? lv[m] : cv; int ti = sw ? li[m] : ci;
        lv[m] = sw ? cv : lv[m]; li[m] = sw ? ci : li[m];
        cv = tv; ci = ti;
      }
    }
  }
  for (int r = 0; r < TPK; ++r) {
    float bv = lv[0]; int bi = li[0];
#pragma unroll
    for (int o = 32; o > 0; o >>= 1) {
      float ov = __shfl_xor(bv, o); int oi = __shfl_xor(bi, o);
      if (lexgt(ov, oi, bv, bi)) { bv = ov; bi = oi; }
    }
    if (lane == 0) { candv[blockIdx.x * TPK + r] = bv; candi[blockIdx.x * TPK + r] = bi; }
    bool mine = (li[0] == bi);
#pragma unroll
    for (int m = 0; m < P1D - 1; ++m) {
      lv[m] = mine ? lv[m + 1] : lv[m];
      li[m] = mine ? li[m + 1] : li[m];
    }
    if (mine) { lv[P1D - 1] = -3.4e38f; li[P1D - 1] = 0x7FFFFFFF; }
  }
}

// phase 2 + final output: tournament merge of 64 sorted lists, then
// out[c] = max_r y[sel_r][c]*val_r.
__global__ __launch_bounds__(64, 1) void topk_p2_final(const float* __restrict__ candv,
                                                       const int* __restrict__ candi,
                                                       const float* __restrict__ y,
                                                       float* __restrict__ out) {
  __shared__ float sv[P1B * TPK];
  __shared__ int si[P1B * TPK];
  __shared__ float sV[TPK];
  __shared__ int sI[TPK];
  int lane = threadIdx.x;  // 64
  for (int k = lane; k < P1B * TPK; k += 64) { sv[k] = candv[k]; si[k] = candi[k]; }
  __syncthreads();
  int myptr = 0;
  for (int r = 0; r < TPK; ++r) {
    bool alive = (myptr < TPK);
    float hv = alive ? sv[lane * TPK + myptr] : -3.4e38f;
    int hi = alive ? si[lane * TPK + myptr] : 0x7FFFFFFF;
    float bv = hv; int bi = hi;
#pragma unroll
    for (int o = 32; o > 0; o >>= 1) {
      float ov = __shfl_xor(bv, o); int oi = __shfl_xor(bi, o);
      if (lexgt(ov, oi, bv, bi)) { bv = ov; bi = oi; }
    }
    if (alive && hi == bi) myptr++;
    if (lane == 0) { sV[r] = bv; sI[r] = bi; }
  }
  __syncthreads();
  float m = -3.4e38f;
  for (int r = 0; r < TPK; ++r)
    m = fmaxf(m, y[(size_t)sI[r] * 64 + lane] * sV[r]);
  out[lane] = m;
}

// ---------------- host orchestration ----------------

extern "C" void kernel_launch(void* const* d_in, const int* in_sizes, int n_in,
                              void* d_out, int out_size, void* d_ws, size_t ws_size,
                              hipStream_t stream) {
  const float* x = (const float*)d_in[0];
  const int* ei = (const int*)d_in[1];
  const float* Wl[5] = {(const float*)d_in[2], (const float*)d_in[4], (const float*)d_in[6],
                        (const float*)d_in[8], (const float*)d_in[10]};
  const float* bl[5] = {(const float*)d_in[3], (const float*)d_in[5], (const float*)d_in[7],
                        (const float*)d_in[9], (const float*)d_in[11]};
  const float* Wm = (const float*)d_in[12];
  const float* bm = (const float*)d_in[13];
  const float* wp = (const float*)d_in[14];
  float* out = (float*)d_out;

  uint8_t* base = (uint8_t*)d_ws;
  size_t off = 0;
  auto alloc = [&](size_t bytes) -> void* {
    void* p = base + off;
    off += (bytes + 255) & ~(size_t)255;
    return p;
  };
  int* deg = (int*)alloc(NN * 4);
  int* rowptr = (int*)alloc((NN + 1) * 4);
  int* cursor = (int*)alloc(NN * 4);
  float* dinv = (float*)alloc(NN * 4);
  int* bsum = (int*)alloc(SCNB * 4);
  int* boff = (int*)alloc(SCNB * 4);
  unsigned int* meta4 = (unsigned int*)alloc((size_t)NNZ * 4);
  float* x0f = (float*)alloc((size_t)NN * 4 * 4);
  uint2* x0h = (uint2*)alloc((size_t)NN * 8);
  uint2* t4ha = (uint2*)alloc((size_t)NN * 8);
  uint2* t4hb = (uint2*)alloc((size_t)NN * 8);
  float* t4f = (float*)alloc((size_t)NN * 4 * 4);
  float* xcur = (float*)alloc((size_t)NN * 64 * 4);
  float* tA = (float*)alloc((size_t)NN * 64 * 4);
  uint4* xh = (uint4*)alloc((size_t)NN * 64 * 2);   // fp16 x copy [NN][64]
  uint4* thA = (uint4*)alloc((size_t)NN * 64 * 2);  // fp16 state ping
  uint4* thB = (uint4*)alloc((size_t)NN * 64 * 2);  // fp16 state pong
  float* scores = (float*)alloc(NN * 4);
  float* candv = (float*)alloc((size_t)P1B * TPK * 4);
  int* candi = (int*)alloc((size_t)P1B * TPK * 4);

  const int* erow = ei;
  const int* ecol = ei + EE;

  init_deg<<<(NN + 255) / 256, 256, 0, stream>>>(deg);
  count_deg<<<(EE + 255) / 256, 256, 0, stream>>>(ecol, deg);
  scan_bsum<<<SCNB, 256, 0, stream>>>(deg, bsum);
  scan_boff<<<1, 256, 0, stream>>>(bsum, boff);
  scan_write<<<SCNB, 256, 0, stream>>>(deg, boff, rowptr, cursor, dinv);
  scatter_csr<<<(NNZ + 255) / 256, 256, 0, stream>>>(erow, ecol, dinv, cursor, meta4);
  extract_x0<<<(NN + 255) / 256, 256, 0, stream>>>(x, (float4*)x0f, x0h);

  const float AL[5] = {0.7f, 0.7f, 0.35f, 0.7f / 3.0f, 0.175f};

  // layer 0 (cin = 4, fp16 state; final sweep emits f32 for dense4)
  {
    float coef = (1.0f - AL[0]) / (float)KK;
    const uint2* tin = x0h;
    uint2* tout = t4ha;
    for (int k = 1; k < KK; ++k) {
      sweep4h<<<(NN + 63) / 64, 256, 0, stream>>>(tin, x0h, nullptr, tout, nullptr, rowptr,
                                                  meta4, 1.0f, 1.0f, 0);
      tin = tout;
      tout = (tout == t4ha) ? t4hb : t4ha;
    }
    sweep4h<<<(NN + 63) / 64, 256, 0, stream>>>(tin, nullptr, (const float4*)x0f, nullptr,
                                                (float4*)t4f, rowptr, meta4, coef, AL[0], 1);
    dense4<<<(NN + 3) / 4, 256, 0, stream>>>(t4f, Wl[0], bl[0], xcur, (unsigned int*)xh);
  }
  // layers 1..4 (cin = 64, fp16 propagation state, 2 nodes/wave, meta4)
  for (int l = 1; l < 5; ++l) {
    float coef = (1.0f - AL[l]) / (float)KK;
    const uint4* tin = xh;
    uint4* tout = thA;
    for (int k = 1; k < KK; ++k) {
      sweep64h<<<(NN + 7) / 8, 256, 0, stream>>>(tin, xh, nullptr, tout, nullptr, rowptr, meta4,
                                                 1.0f, 1.0f, 0);
      tin = tout;
      tout = (tout == thA) ? thB : thA;
    }
    // final sweep: gather fp16, combine with f32 x, write f32
    sweep64h<<<(NN + 7) / 8, 256, 0, stream>>>(tin, nullptr, (const float4*)xcur, nullptr,
                                               (float4*)tA, rowptr, meta4, coef, AL[l], 1);
    dense64<<<(NN + DN - 1) / DN, 256, 0, stream>>>(tA, Wl[l], bl[l], xcur, xcur,
                                                    (l < 4) ? xh : nullptr, 1, (l >= 2) ? 1 : 0);
  }
  // final projection y = x @ Wm.T + bm  -> tA
  dense64<<<(NN + DN - 1) / DN, 256, 0, stream>>>(xcur, Wm, bm, nullptr, tA, nullptr, 0, 0);
  score_k<<<(NN + 3) / 4, 256, 0, stream>>>(tA, wp, scores);
  topk_p1<<<P1B, 64, 0, stream>>>(scores, candv, candi);
  topk_p2_final<<<1, 64, 0, stream>>>(candv, candi, tA, out);
}

// Round 14
// 1957.966 us; speedup vs baseline: 1.0975x; 1.0975x over previous
//
#include <hip/hip_runtime.h>
#include <hip/hip_fp16.h>
#include <cstdint>
#include <cstddef>

#define NN 50000
#define EE 800000
#define NNZ (NN + EE)
#define KK 20
#define TPK 30
#define P1B 64
#define P1CH ((NN + P1B - 1) / P1B)  // 782
#define P1D 13                       // ceil(P1CH/64): max candidates a lane ingests
#define SCB 256
#define SCNB ((NN + SCB - 1) / SCB)  // 196

// ---------------- fp16 helpers ----------------

__device__ __forceinline__ float2 h2f(unsigned int u) {
  __half2 h = *reinterpret_cast<__half2*>(&u);
  return __half22float2(h);
}
__device__ __forceinline__ unsigned int f2h(float a, float b) {
  __half2 h = __floats2half2_rn(a, b);
  return *reinterpret_cast<unsigned int*>(&h);
}
__device__ __forceinline__ float wgt_of(unsigned int m) {  // high 16 bits = fp16 weight
  __half_raw hr;
  hr.x = (unsigned short)(m >> 16);
  return __half2float(__half(hr));
}

// ---------------- preprocessing ----------------

__global__ __launch_bounds__(256) void init_deg(int* deg) {
  int t = blockIdx.x * 256 + threadIdx.x;
  if (t < NN) deg[t] = 1;  // self-loop
}

__global__ __launch_bounds__(256) void count_deg(const int* __restrict__ ecol, int* deg) {
  int t = blockIdx.x * 256 + threadIdx.x;
  if (t < EE) atomicAdd(&deg[ecol[t]], 1);
}

__global__ __launch_bounds__(256) void scan_bsum(const int* __restrict__ deg, int* __restrict__ bsum) {
  __shared__ int red[256];
  int tid = threadIdx.x;
  int t = blockIdx.x * 256 + tid;
  red[tid] = (t < NN) ? deg[t] : 0;
  __syncthreads();
  for (int o = 128; o > 0; o >>= 1) {
    if (tid < o) red[tid] += red[tid + o];
    __syncthreads();
  }
  if (tid == 0) bsum[blockIdx.x] = red[0];
}

__global__ __launch_bounds__(256) void scan_boff(const int* __restrict__ bsum, int* __restrict__ boff) {
  __shared__ int s[256];
  int tid = threadIdx.x;
  int own = (tid < SCNB) ? bsum[tid] : 0;
  s[tid] = own;
  __syncthreads();
  for (int o = 1; o < 256; o <<= 1) {
    int v = s[tid];
    int u = (tid >= o) ? s[tid - o] : 0;
    __syncthreads();
    s[tid] = v + u;
    __syncthreads();
  }
  if (tid < SCNB) boff[tid] = s[tid] - own;  // exclusive
}

__global__ __launch_bounds__(256) void scan_write(const int* __restrict__ deg,
                                                  const int* __restrict__ boff,
                                                  int* __restrict__ rowptr, int* __restrict__ cursor,
                                                  float* __restrict__ dinv) {
  __shared__ int s[256];
  int tid = threadIdx.x;
  int t = blockIdx.x * 256 + tid;
  int d = (t < NN) ? deg[t] : 0;
  s[tid] = d;
  __syncthreads();
  for (int o = 1; o < 256; o <<= 1) {
    int v = s[tid];
    int u = (tid >= o) ? s[tid - o] : 0;
    __syncthreads();
    s[tid] = v + u;
    __syncthreads();
  }
  if (t < NN) {
    int excl = boff[blockIdx.x] + s[tid] - d;
    rowptr[t] = excl;
    cursor[t] = excl;
    dinv[t] = 1.0f / sqrtf((float)d);
    if (t == NN - 1) rowptr[NN] = excl + d;
  }
}

// meta4: packed edge record = (fp16 weight << 16) | src  (src < 65536 since NN=50000)
__global__ __launch_bounds__(256) void scatter_csr(const int* __restrict__ erow,
                                                   const int* __restrict__ ecol,
                                                   const float* __restrict__ dinv, int* cursor,
                                                   unsigned int* __restrict__ meta4) {
  int t = blockIdx.x * 256 + threadIdx.x;
  if (t < EE) {
    int r = erow[t], c = ecol[t];
    int p = atomicAdd(&cursor[c], 1);
    __half_raw hr = __half_raw(__float2half_rn(dinv[r] * dinv[c]));
    meta4[p] = ((unsigned int)hr.x << 16) | (unsigned int)r;
  } else if (t < NNZ) {
    int i = t - EE;
    int p = atomicAdd(&cursor[i], 1);
    __half_raw hr = __half_raw(__float2half_rn(dinv[i] * dinv[i]));
    meta4[p] = ((unsigned int)hr.x << 16) | (unsigned int)i;
  }
}

__global__ __launch_bounds__(256) void extract_x0(const float* __restrict__ x, float4* __restrict__ x0) {
  int t = blockIdx.x * 256 + threadIdx.x;
  if (t < NN) x0[t] = *(const float4*)&x[(size_t)t * 8];
}

// ---------------- propagation sweeps ----------------
// tout[v] = aacc * sum_e nrm[e]*tin[src[e]] + axc * xin[v]

// 64-channel fp16 sweep, TWO nodes per wave, trip-unrolled x2:
// FOUR independent 128B row-gathers in flight per wave (qa0/qb0/qa1/qb1).
// meta4 packed: one __shfl per edge. Lane = (e8 edge-slot, c8 channel-group).
// All trip counts wave-uniform; lanes >= nj hold m=0 (weight 0).
__global__ __launch_bounds__(256) void sweep64h(const uint4* __restrict__ tinq,
                                                const uint4* __restrict__ xinq,
                                                const float4* __restrict__ xinf,
                                                uint4* __restrict__ touth,
                                                float4* __restrict__ toutf,
                                                const int* __restrict__ rowptr,
                                                const unsigned int* __restrict__ meta4,
                                                float aacc, float axc, int isFinal) {
  int lane = threadIdx.x & 63;
  int w = threadIdx.x >> 6;
  int v0 = (blockIdx.x * 4 + w) * 2;  // grid exact: (NN/8) blocks, NN even
  int v1 = v0 + 1;
  if (v0 >= NN) return;
  int c8 = lane & 7;
  int e8 = lane >> 3;
  int s0 = rowptr[v0];
  int s1 = rowptr[v0 + 1];
  int e1 = rowptr[v0 + 2];
  int d0 = s1 - s0, d1 = e1 - s1;
  int nj0 = (d0 > 64) ? 64 : d0;
  int nj1 = (d1 > 64) ? 64 : d1;
  unsigned int mA = (lane < nj0) ? meta4[s0 + lane] : 0u;
  unsigned int mB = (lane < nj1) ? meta4[s1 + lane] : 0u;
  float a0 = 0.f, a1 = 0.f, a2 = 0.f, a3 = 0.f;
  float a4 = 0.f, a5 = 0.f, a6 = 0.f, a7 = 0.f;
  float b0 = 0.f, b1 = 0.f, b2 = 0.f, b3 = 0.f;
  float b4 = 0.f, b5 = 0.f, b6 = 0.f, b7 = 0.f;
  int T0 = (nj0 + 7) >> 3;
  int T1 = (nj1 + 7) >> 3;
  int Tc = (T0 < T1) ? T0 : T1;
  int t = 0;
  for (; t + 1 < Tc; t += 2) {  // 4 gathers in flight
    int j0 = e8 + 8 * t;
    int j1 = j0 + 8;
    unsigned int ma0 = __shfl(mA, j0);
    unsigned int mb0 = __shfl(mB, j0);
    unsigned int ma1 = __shfl(mA, j1);
    unsigned int mb1 = __shfl(mB, j1);
    uint4 qa0 = tinq[(size_t)(ma0 & 0xffffu) * 8 + c8];
    uint4 qb0 = tinq[(size_t)(mb0 & 0xffffu) * 8 + c8];
    uint4 qa1 = tinq[(size_t)(ma1 & 0xffffu) * 8 + c8];
    uint4 qb1 = tinq[(size_t)(mb1 & 0xffffu) * 8 + c8];
    float wa0 = wgt_of(ma0), wb0 = wgt_of(mb0);
    float wa1 = wgt_of(ma1), wb1 = wgt_of(mb1);
    float2 f;
    f = h2f(qa0.x); a0 = fmaf(wa0, f.x, a0); a1 = fmaf(wa0, f.y, a1);
    f = h2f(qa0.y); a2 = fmaf(wa0, f.x, a2); a3 = fmaf(wa0, f.y, a3);
    f = h2f(qa0.z); a4 = fmaf(wa0, f.x, a4); a5 = fmaf(wa0, f.y, a5);
    f = h2f(qa0.w); a6 = fmaf(wa0, f.x, a6); a7 = fmaf(wa0, f.y, a7);
    f = h2f(qb0.x); b0 = fmaf(wb0, f.x, b0); b1 = fmaf(wb0, f.y, b1);
    f = h2f(qb0.y); b2 = fmaf(wb0, f.x, b2); b3 = fmaf(wb0, f.y, b3);
    f = h2f(qb0.z); b4 = fmaf(wb0, f.x, b4); b5 = fmaf(wb0, f.y, b5);
    f = h2f(qb0.w); b6 = fmaf(wb0, f.x, b6); b7 = fmaf(wb0, f.y, b7);
    f = h2f(qa1.x); a0 = fmaf(wa1, f.x, a0); a1 = fmaf(wa1, f.y, a1);
    f = h2f(qa1.y); a2 = fmaf(wa1, f.x, a2); a3 = fmaf(wa1, f.y, a3);
    f = h2f(qa1.z); a4 = fmaf(wa1, f.x, a4); a5 = fmaf(wa1, f.y, a5);
    f = h2f(qa1.w); a6 = fmaf(wa1, f.x, a6); a7 = fmaf(wa1, f.y, a7);
    f = h2f(qb1.x); b0 = fmaf(wb1, f.x, b0); b1 = fmaf(wb1, f.y, b1);
    f = h2f(qb1.y); b2 = fmaf(wb1, f.x, b2); b3 = fmaf(wb1, f.y, b3);
    f = h2f(qb1.z); b4 = fmaf(wb1, f.x, b4); b5 = fmaf(wb1, f.y, b5);
    f = h2f(qb1.w); b6 = fmaf(wb1, f.x, b6); b7 = fmaf(wb1, f.y, b7);
  }
  for (; t < Tc; ++t) {  // odd-trip remainder: 2 gathers in flight
    int j = e8 + 8 * t;
    unsigned int ma = __shfl(mA, j);
    unsigned int mb = __shfl(mB, j);
    uint4 qa = tinq[(size_t)(ma & 0xffffu) * 8 + c8];
    uint4 qb = tinq[(size_t)(mb & 0xffffu) * 8 + c8];
    float wa = wgt_of(ma), wb = wgt_of(mb);
    float2 f;
    f = h2f(qa.x); a0 = fmaf(wa, f.x, a0); a1 = fmaf(wa, f.y, a1);
    f = h2f(qa.y); a2 = fmaf(wa, f.x, a2); a3 = fmaf(wa, f.y, a3);
    f = h2f(qa.z); a4 = fmaf(wa, f.x, a4); a5 = fmaf(wa, f.y, a5);
    f = h2f(qa.w); a6 = fmaf(wa, f.x, a6); a7 = fmaf(wa, f.y, a7);
    f = h2f(qb.x); b0 = fmaf(wb, f.x, b0); b1 = fmaf(wb, f.y, b1);
    f = h2f(qb.y); b2 = fmaf(wb, f.x, b2); b3 = fmaf(wb, f.y, b3);
    f = h2f(qb.z); b4 = fmaf(wb, f.x, b4); b5 = fmaf(wb, f.y, b5);
    f = h2f(qb.w); b6 = fmaf(wb, f.x, b6); b7 = fmaf(wb, f.y, b7);
  }
  for (; t < T0; ++t) {  // drain A
    int j = e8 + 8 * t;
    unsigned int ma = __shfl(mA, j);
    float wa = wgt_of(ma);
    uint4 qa = tinq[(size_t)(ma & 0xffffu) * 8 + c8];
    float2 f;
    f = h2f(qa.x); a0 = fmaf(wa, f.x, a0); a1 = fmaf(wa, f.y, a1);
    f = h2f(qa.y); a2 = fmaf(wa, f.x, a2); a3 = fmaf(wa, f.y, a3);
    f = h2f(qa.z); a4 = fmaf(wa, f.x, a4); a5 = fmaf(wa, f.y, a5);
    f = h2f(qa.w); a6 = fmaf(wa, f.x, a6); a7 = fmaf(wa, f.y, a7);
  }
  for (; t < T1; ++t) {  // drain B
    int j = e8 + 8 * t;
    unsigned int mb = __shfl(mB, j);
    float wb = wgt_of(mb);
    uint4 qb = tinq[(size_t)(mb & 0xffffu) * 8 + c8];
    float2 f;
    f = h2f(qb.x); b0 = fmaf(wb, f.x, b0); b1 = fmaf(wb, f.y, b1);
    f = h2f(qb.y); b2 = fmaf(wb, f.x, b2); b3 = fmaf(wb, f.y, b3);
    f = h2f(qb.z); b4 = fmaf(wb, f.x, b4); b5 = fmaf(wb, f.y, b5);
    f = h2f(qb.w); b6 = fmaf(wb, f.x, b6); b7 = fmaf(wb, f.y, b7);
  }
  // cold overflow path (deg > 64)
  if (d0 > 64) {
    int e = s0 + d0;
    for (int c2 = s0 + 64; c2 < e; c2 += 64) {
      int nj2 = e - c2; if (nj2 > 64) nj2 = 64;
      unsigned int mX = (lane < nj2) ? meta4[c2 + lane] : 0u;
      int T2 = (nj2 + 7) >> 3;
      for (int t2 = 0; t2 < T2; ++t2) {
        int j = e8 + 8 * t2;
        unsigned int ma = __shfl(mX, j);
        float wa = wgt_of(ma);
        uint4 qa = tinq[(size_t)(ma & 0xffffu) * 8 + c8];
        float2 f;
        f = h2f(qa.x); a0 = fmaf(wa, f.x, a0); a1 = fmaf(wa, f.y, a1);
        f = h2f(qa.y); a2 = fmaf(wa, f.x, a2); a3 = fmaf(wa, f.y, a3);
        f = h2f(qa.z); a4 = fmaf(wa, f.x, a4); a5 = fmaf(wa, f.y, a5);
        f = h2f(qa.w); a6 = fmaf(wa, f.x, a6); a7 = fmaf(wa, f.y, a7);
      }
    }
  }
  if (d1 > 64) {
    int e = s1 + d1;
    for (int c2 = s1 + 64; c2 < e; c2 += 64) {
      int nj2 = e - c2; if (nj2 > 64) nj2 = 64;
      unsigned int mX = (lane < nj2) ? meta4[c2 + lane] : 0u;
      int T2 = (nj2 + 7) >> 3;
      for (int t2 = 0; t2 < T2; ++t2) {
        int j = e8 + 8 * t2;
        unsigned int mb = __shfl(mX, j);
        float wb = wgt_of(mb);
        uint4 qb = tinq[(size_t)(mb & 0xffffu) * 8 + c8];
        float2 f;
        f = h2f(qb.x); b0 = fmaf(wb, f.x, b0); b1 = fmaf(wb, f.y, b1);
        f = h2f(qb.y); b2 = fmaf(wb, f.x, b2); b3 = fmaf(wb, f.y, b3);
        f = h2f(qb.z); b4 = fmaf(wb, f.x, b4); b5 = fmaf(wb, f.y, b5);
        f = h2f(qb.w); b6 = fmaf(wb, f.x, b6); b7 = fmaf(wb, f.y, b7);
      }
    }
  }
  // reduce across the 8 e-slots (lane bits 3..5), both nodes interleaved
#pragma unroll
  for (int o = 8; o <= 32; o <<= 1) {
    a0 += __shfl_xor(a0, o); b0 += __shfl_xor(b0, o);
    a1 += __shfl_xor(a1, o); b1 += __shfl_xor(b1, o);
    a2 += __shfl_xor(a2, o); b2 += __shfl_xor(b2, o);
    a3 += __shfl_xor(a3, o); b3 += __shfl_xor(b3, o);
    a4 += __shfl_xor(a4, o); b4 += __shfl_xor(b4, o);
    a5 += __shfl_xor(a5, o); b5 += __shfl_xor(b5, o);
    a6 += __shfl_xor(a6, o); b6 += __shfl_xor(b6, o);
    a7 += __shfl_xor(a7, o); b7 += __shfl_xor(b7, o);
  }
  if (e8 == 0) {
    if (!isFinal) {
      uint4 xq0 = xinq[(size_t)v0 * 8 + c8];
      uint4 xq1 = xinq[(size_t)v1 * 8 + c8];
      float2 f;
      uint4 r;
      f = h2f(xq0.x); r.x = f2h(a0 + f.x, a1 + f.y);
      f = h2f(xq0.y); r.y = f2h(a2 + f.x, a3 + f.y);
      f = h2f(xq0.z); r.z = f2h(a4 + f.x, a5 + f.y);
      f = h2f(xq0.w); r.w = f2h(a6 + f.x, a7 + f.y);
      touth[(size_t)v0 * 8 + c8] = r;
      f = h2f(xq1.x); r.x = f2h(b0 + f.x, b1 + f.y);
      f = h2f(xq1.y); r.y = f2h(b2 + f.x, b3 + f.y);
      f = h2f(xq1.z); r.z = f2h(b4 + f.x, b5 + f.y);
      f = h2f(xq1.w); r.w = f2h(b6 + f.x, b7 + f.y);
      touth[(size_t)v1 * 8 + c8] = r;
    } else {
      float4 x0v = xinf[(size_t)v0 * 16 + c8 * 2];
      float4 x1v = xinf[(size_t)v0 * 16 + c8 * 2 + 1];
      float4 r0, r1;
      r0.x = aacc * a0 + axc * x0v.x; r0.y = aacc * a1 + axc * x0v.y;
      r0.z = aacc * a2 + axc * x0v.z; r0.w = aacc * a3 + axc * x0v.w;
      r1.x = aacc * a4 + axc * x1v.x; r1.y = aacc * a5 + axc * x1v.y;
      r1.z = aacc * a6 + axc * x1v.z; r1.w = aacc * a7 + axc * x1v.w;
      toutf[(size_t)v0 * 16 + c8 * 2] = r0;
      toutf[(size_t)v0 * 16 + c8 * 2 + 1] = r1;
      float4 y0v = xinf[(size_t)v1 * 16 + c8 * 2];
      float4 y1v = xinf[(size_t)v1 * 16 + c8 * 2 + 1];
      r0.x = aacc * b0 + axc * y0v.x; r0.y = aacc * b1 + axc * y0v.y;
      r0.z = aacc * b2 + axc * y0v.z; r0.w = aacc * b3 + axc * y0v.w;
      r1.x = aacc * b4 + axc * y1v.x; r1.y = aacc * b5 + axc * y1v.y;
      r1.z = aacc * b6 + axc * y1v.z; r1.w = aacc * b7 + axc * y1v.w;
      toutf[(size_t)v1 * 16 + c8 * 2] = r0;
      toutf[(size_t)v1 * 16 + c8 * 2 + 1] = r1;
    }
  }
}

// 4-channel f32: wave = 16 nodes x 4 edge slots; unrolled x4; meta4 packed.
__global__ __launch_bounds__(256) void sweep4(const float4* __restrict__ tin,
                                              const float4* __restrict__ xin,
                                              float4* __restrict__ tout,
                                              const int* __restrict__ rowptr,
                                              const unsigned int* __restrict__ meta4,
                                              float aacc, float axc) {
  int lane = threadIdx.x & 63;
  int w = threadIdx.x >> 6;
  int n16 = lane & 15;
  int e4 = lane >> 4;
  int v = (blockIdx.x * 4 + w) * 16 + n16;
  int vv = (v < NN) ? v : (NN - 1);
  int s = rowptr[vv], e = rowptr[vv + 1];
  float a0 = 0.f, a1 = 0.f, a2 = 0.f, a3 = 0.f;
  float b0 = 0.f, b1 = 0.f, b2 = 0.f, b3 = 0.f;
  int i = s + e4;
  for (; i + 12 < e; i += 16) {
    unsigned int m0 = meta4[i];
    unsigned int m1 = meta4[i + 4];
    unsigned int m2 = meta4[i + 8];
    unsigned int m3 = meta4[i + 12];
    float w0 = wgt_of(m0), w1 = wgt_of(m1), w2 = wgt_of(m2), w3 = wgt_of(m3);
    float4 t0 = tin[m0 & 0xffffu];
    float4 t1 = tin[m1 & 0xffffu];
    float4 t2 = tin[m2 & 0xffffu];
    float4 t3 = tin[m3 & 0xffffu];
    a0 = fmaf(w0, t0.x, a0); a1 = fmaf(w0, t0.y, a1);
    a2 = fmaf(w0, t0.z, a2); a3 = fmaf(w0, t0.w, a3);
    b0 = fmaf(w1, t1.x, b0); b1 = fmaf(w1, t1.y, b1);
    b2 = fmaf(w1, t1.z, b2); b3 = fmaf(w1, t1.w, b3);
    a0 = fmaf(w2, t2.x, a0); a1 = fmaf(w2, t2.y, a1);
    a2 = fmaf(w2, t2.z, a2); a3 = fmaf(w2, t2.w, a3);
    b0 = fmaf(w3, t3.x, b0); b1 = fmaf(w3, t3.y, b1);
    b2 = fmaf(w3, t3.z, b2); b3 = fmaf(w3, t3.w, b3);
  }
  for (; i < e; i += 4) {
    unsigned int m0 = meta4[i];
    float w0 = wgt_of(m0);
    float4 t0 = tin[m0 & 0xffffu];
    a0 = fmaf(w0, t0.x, a0); a1 = fmaf(w0, t0.y, a1);
    a2 = fmaf(w0, t0.z, a2); a3 = fmaf(w0, t0.w, a3);
  }
  a0 += b0; a1 += b1; a2 += b2; a3 += b3;
  a0 += __shfl_xor(a0, 16); a1 += __shfl_xor(a1, 16);
  a2 += __shfl_xor(a2, 16); a3 += __shfl_xor(a3, 16);
  a0 += __shfl_xor(a0, 32); a1 += __shfl_xor(a1, 32);
  a2 += __shfl_xor(a2, 32); a3 += __shfl_xor(a3, 32);
  if (e4 == 0 && v < NN) {
    float4 xv = xin[v];
    float4 o;
    o.x = aacc * a0 + axc * xv.x;
    o.y = aacc * a1 + axc * xv.y;
    o.z = aacc * a2 + axc * xv.z;
    o.w = aacc * a3 + axc * xv.w;
    tout[v] = o;
  }
}

// ---------------- dense layers ----------------

// emits f32 out AND fp16 copy for the next layer's propagation
__global__ __launch_bounds__(256) void dense4(const float* __restrict__ h4,
                                              const float* __restrict__ W,  // [64][4]
                                              const float* __restrict__ b,
                                              float* __restrict__ out,
                                              unsigned int* __restrict__ outh) {
  __shared__ float sWt[4 * 64];
  int tid = threadIdx.x;
  {
    int j = tid >> 2, c = tid & 3;
    sWt[c * 64 + j] = W[tid];
  }
  __syncthreads();
  int lane = tid & 63, w = tid >> 6;
  int n = blockIdx.x * 4 + w;
  if (n >= NN) return;  // wave-uniform
  float acc = b[lane];
#pragma unroll
  for (int c = 0; c < 4; ++c)
    acc = fmaf(h4[(size_t)n * 4 + c], sWt[c * 64 + lane], acc);
  acc = fmaxf(acc, 0.f);
  out[(size_t)n * 64 + lane] = acc;
  int p = lane & 31;
  float va = __shfl(acc, 2 * p);
  float vb = __shfl(acc, 2 * p + 1);
  if (lane < 32) outh[(size_t)n * 32 + lane] = f2h(va, vb);
}

// 128 nodes per block; thread = (node j, out-quarter q) covering nodes {j, j+64}
#define DN 128
__global__ __launch_bounds__(256) void dense64(const float* __restrict__ h,
                                               const float* __restrict__ W,  // [64][64]
                                               const float* __restrict__ b,
                                               const float* __restrict__ resid,
                                               float* __restrict__ out,
                                               uint4* __restrict__ outh,  // optional fp16 copy
                                               int doRelu, int doResid) {
  __shared__ float sX[64 * 130];
  __shared__ float sWt[64 * 68];
  int tid = threadIdx.x;
  int base = blockIdx.x * DN;
  for (int i = tid; i < 64 * 64; i += 256) {
    int o = i >> 6, c = i & 63;
    sWt[c * 68 + o] = W[i];
  }
  for (int i = tid; i < DN * 64; i += 256) {
    int node = i >> 6, c = i & 63;
    int n = base + node;
    sX[c * 130 + node] = (n < NN) ? h[(size_t)n * 64 + c] : 0.f;
  }
  __syncthreads();
  int j = tid & 63;
  int q = tid >> 6;
  float acc0[16], acc1[16];
#pragma unroll
  for (int o = 0; o < 16; ++o) { acc0[o] = b[q * 16 + o]; acc1[o] = acc0[o]; }
  for (int c = 0; c < 64; ++c) {
    float x0 = sX[c * 130 + j];
    float x1 = sX[c * 130 + 64 + j];
#pragma unroll
    for (int o4 = 0; o4 < 4; ++o4) {
      float4 wv = *(const float4*)&sWt[c * 68 + q * 16 + o4 * 4];
      acc0[o4 * 4 + 0] = fmaf(x0, wv.x, acc0[o4 * 4 + 0]);
      acc0[o4 * 4 + 1] = fmaf(x0, wv.y, acc0[o4 * 4 + 1]);
      acc0[o4 * 4 + 2] = fmaf(x0, wv.z, acc0[o4 * 4 + 2]);
      acc0[o4 * 4 + 3] = fmaf(x0, wv.w, acc0[o4 * 4 + 3]);
      acc1[o4 * 4 + 0] = fmaf(x1, wv.x, acc1[o4 * 4 + 0]);
      acc1[o4 * 4 + 1] = fmaf(x1, wv.y, acc1[o4 * 4 + 1]);
      acc1[o4 * 4 + 2] = fmaf(x1, wv.z, acc1[o4 * 4 + 2]);
      acc1[o4 * 4 + 3] = fmaf(x1, wv.w, acc1[o4 * 4 + 3]);
    }
  }
  int n0 = base + j, n1 = base + 64 + j;
#pragma unroll
  for (int half = 0; half < 2; ++half) {
    int n = half ? n1 : n0;
    float* acc = half ? acc1 : acc0;
    if (n < NN) {
      if (doRelu) {
#pragma unroll
        for (int o = 0; o < 16; ++o) acc[o] = fmaxf(acc[o], 0.f);
      }
      if (doResid) {
#pragma unroll
        for (int o4 = 0; o4 < 4; ++o4) {
          float4 rv = *(const float4*)&resid[(size_t)n * 64 + q * 16 + o4 * 4];
          acc[o4 * 4 + 0] += rv.x; acc[o4 * 4 + 1] += rv.y;
          acc[o4 * 4 + 2] += rv.z; acc[o4 * 4 + 3] += rv.w;
        }
      }
#pragma unroll
      for (int o4 = 0; o4 < 4; ++o4) {
        float4 r;
        r.x = acc[o4 * 4 + 0]; r.y = acc[o4 * 4 + 1];
        r.z = acc[o4 * 4 + 2]; r.w = acc[o4 * 4 + 3];
        *(float4*)&out[(size_t)n * 64 + q * 16 + o4 * 4] = r;
      }
      if (outh) {
        uint4 u;
        u.x = f2h(acc[0], acc[1]);  u.y = f2h(acc[2], acc[3]);
        u.z = f2h(acc[4], acc[5]);  u.w = f2h(acc[6], acc[7]);
        outh[(size_t)n * 8 + q * 2] = u;
        u.x = f2h(acc[8], acc[9]);  u.y = f2h(acc[10], acc[11]);
        u.z = f2h(acc[12], acc[13]); u.w = f2h(acc[14], acc[15]);
        outh[(size_t)n * 8 + q * 2 + 1] = u;
      }
    }
  }
}

// ---------------- scoring / selection / output ----------------

__global__ __launch_bounds__(256) void score_k(const float* __restrict__ y,
                                               const float* __restrict__ wp,
                                               float* __restrict__ scores) {
  int tid = threadIdx.x;
  int lane = tid & 63, w = tid >> 6;
  int n = blockIdx.x * 4 + w;
  if (n >= NN) return;
  float wv = wp[lane];
  float s = wv * wv;
#pragma unroll
  for (int o = 32; o > 0; o >>= 1) s += __shfl_xor(s, o);
  float invn = 1.0f / sqrtf(s);
  float p = y[(size_t)n * 64 + lane] * wv;
#pragma unroll
  for (int o = 32; o > 0; o >>= 1) p += __shfl_xor(p, o);
  if (lane == 0) scores[n] = tanhf(p * invn);
}

__device__ __forceinline__ bool lexgt(float v1, int i1, float v2, int i2) {
  return (v1 > v2) || (v1 == v2 && i1 < i2);
}

// phase 1: 64 single-wave blocks, each emits its chunk's SORTED top-30.
__global__ __launch_bounds__(64, 1) void topk_p1(const float* __restrict__ score,
                                                 float* __restrict__ candv,
                                                 int* __restrict__ candi) {
  int lane = threadIdx.x;
  int base = blockIdx.x * P1CH;
  float lv[P1D]; int li[P1D];
#pragma unroll
  for (int k = 0; k < P1D; ++k) { lv[k] = -3.4e38f; li[k] = 0x7FFFFFFF; }
  for (int k = lane; k < P1CH; k += 64) {
    int idx = base + k;
    if (idx >= NN) break;
    float v = score[idx];
    if (lexgt(v, idx, lv[P1D - 1], li[P1D - 1])) {
      float cv = v; int ci = idx;
#pragma unroll
      for (int m = 0; m < P1D; ++m) {
        bool sw = lexgt(cv, ci, lv[m], li[m]);
        float tv = sw ? lv[m] : cv; int ti = sw ? li[m] : ci;
        lv[m] = sw ? cv : lv[m]; li[m] = sw ? ci : li[m];
        cv = tv; ci = ti;
      }
    }
  }
  for (int r = 0; r < TPK; ++r) {
    float bv = lv[0]; int bi = li[0];
#pragma unroll
    for (int o = 32; o > 0; o >>= 1) {
      float ov = __shfl_xor(bv, o); int oi = __shfl_xor(bi, o);
      if (lexgt(ov, oi, bv, bi)) { bv = ov; bi = oi; }
    }
    if (lane == 0) { candv[blockIdx.x * TPK + r] = bv; candi[blockIdx.x * TPK + r] = bi; }
    bool mine = (li[0] == bi);
#pragma unroll
    for (int m = 0; m < P1D - 1; ++m) {
      lv[m] = mine ? lv[m + 1] : lv[m];
      li[m] = mine ? li[m + 1] : li[m];
    }
    if (mine) { lv[P1D - 1] = -3.4e38f; li[P1D - 1] = 0x7FFFFFFF; }
  }
}

// phase 2 + final output: tournament merge of 64 sorted lists, then
// out[c] = max_r y[sel_r][c]*val_r.
__global__ __launch_bounds__(64, 1) void topk_p2_final(const float* __restrict__ candv,
                                                       const int* __restrict__ candi,
                                                       const float* __restrict__ y,
                                                       float* __restrict__ out) {
  __shared__ float sv[P1B * TPK];
  __shared__ int si[P1B * TPK];
  __shared__ float sV[TPK];
  __shared__ int sI[TPK];
  int lane = threadIdx.x;  // 64
  for (int k = lane; k < P1B * TPK; k += 64) { sv[k] = candv[k]; si[k] = candi[k]; }
  __syncthreads();
  int myptr = 0;
  for (int r = 0; r < TPK; ++r) {
    bool alive = (myptr < TPK);
    float hv = alive ? sv[lane * TPK + myptr] : -3.4e38f;
    int hi = alive ? si[lane * TPK + myptr] : 0x7FFFFFFF;
    float bv = hv; int bi = hi;
#pragma unroll
    for (int o = 32; o > 0; o >>= 1) {
      float ov = __shfl_xor(bv, o); int oi = __shfl_xor(bi, o);
      if (lexgt(ov, oi, bv, bi)) { bv = ov; bi = oi; }
    }
    if (alive && hi == bi) myptr++;
    if (lane == 0) { sV[r] = bv; sI[r] = bi; }
  }
  __syncthreads();
  float m = -3.4e38f;
  for (int r = 0; r < TPK; ++r)
    m = fmaxf(m, y[(size_t)sI[r] * 64 + lane] * sV[r]);
  out[lane] = m;
}

// ---------------- host orchestration ----------------

extern "C" void kernel_launch(void* const* d_in, const int* in_sizes, int n_in,
                              void* d_out, int out_size, void* d_ws, size_t ws_size,
                              hipStream_t stream) {
  const float* x = (const float*)d_in[0];
  const int* ei = (const int*)d_in[1];
  const float* Wl[5] = {(const float*)d_in[2], (const float*)d_in[4], (const float*)d_in[6],
                        (const float*)d_in[8], (const float*)d_in[10]};
  const float* bl[5] = {(const float*)d_in[3], (const float*)d_in[5], (const float*)d_in[7],
                        (const float*)d_in[9], (const float*)d_in[11]};
  const float* Wm = (const float*)d_in[12];
  const float* bm = (const float*)d_in[13];
  const float* wp = (const float*)d_in[14];
  float* out = (float*)d_out;

  uint8_t* base = (uint8_t*)d_ws;
  size_t off = 0;
  auto alloc = [&](size_t bytes) -> void* {
    void* p = base + off;
    off += (bytes + 255) & ~(size_t)255;
    return p;
  };
  int* deg = (int*)alloc(NN * 4);
  int* rowptr = (int*)alloc((NN + 1) * 4);
  int* cursor = (int*)alloc(NN * 4);
  float* dinv = (float*)alloc(NN * 4);
  int* bsum = (int*)alloc(SCNB * 4);
  int* boff = (int*)alloc(SCNB * 4);
  unsigned int* meta4 = (unsigned int*)alloc((size_t)NNZ * 4);
  float* x0 = (float*)alloc((size_t)NN * 4 * 4);
  float* t4a = (float*)alloc((size_t)NN * 4 * 4);
  float* t4b = (float*)alloc((size_t)NN * 4 * 4);
  float* xcur = (float*)alloc((size_t)NN * 64 * 4);
  float* tA = (float*)alloc((size_t)NN * 64 * 4);
  uint4* xh = (uint4*)alloc((size_t)NN * 64 * 2);   // fp16 x copy [NN][64]
  uint4* thA = (uint4*)alloc((size_t)NN * 64 * 2);  // fp16 state ping
  uint4* thB = (uint4*)alloc((size_t)NN * 64 * 2);  // fp16 state pong
  float* scores = (float*)alloc(NN * 4);
  float* candv = (float*)alloc((size_t)P1B * TPK * 4);
  int* candi = (int*)alloc((size_t)P1B * TPK * 4);

  const int* erow = ei;
  const int* ecol = ei + EE;

  init_deg<<<(NN + 255) / 256, 256, 0, stream>>>(deg);
  count_deg<<<(EE + 255) / 256, 256, 0, stream>>>(ecol, deg);
  scan_bsum<<<SCNB, 256, 0, stream>>>(deg, bsum);
  scan_boff<<<1, 256, 0, stream>>>(bsum, boff);
  scan_write<<<SCNB, 256, 0, stream>>>(deg, boff, rowptr, cursor, dinv);
  scatter_csr<<<(NNZ + 255) / 256, 256, 0, stream>>>(erow, ecol, dinv, cursor, meta4);
  extract_x0<<<(NN + 255) / 256, 256, 0, stream>>>(x, (float4*)x0);

  const float AL[5] = {0.7f, 0.7f, 0.35f, 0.7f / 3.0f, 0.175f};

  // layer 0 (cin = 4, f32 — footprint is L2-resident)
  {
    float coef = (1.0f - AL[0]) / (float)KK;
    const float* tin = x0;
    float* tout = t4a;
    for (int k = 1; k <= KK; ++k) {
      float aacc = (k == KK) ? coef : 1.0f;
      float axc = (k == KK) ? AL[0] : 1.0f;
      sweep4<<<(NN + 63) / 64, 256, 0, stream>>>((const float4*)tin, (const float4*)x0,
                                                 (float4*)tout, rowptr, meta4, aacc, axc);
      tin = tout;
      tout = (tout == t4a) ? t4b : t4a;
    }
    dense4<<<(NN + 3) / 4, 256, 0, stream>>>(tin, Wl[0], bl[0], xcur, (unsigned int*)xh);
  }
  // layers 1..4 (cin = 64, fp16 propagation state, 2 nodes/wave, meta4)
  for (int l = 1; l < 5; ++l) {
    float coef = (1.0f - AL[l]) / (float)KK;
    const uint4* tin = xh;
    uint4* tout = thA;
    for (int k = 1; k < KK; ++k) {
      sweep64h<<<(NN + 7) / 8, 256, 0, stream>>>(tin, xh, nullptr, tout, nullptr, rowptr, meta4,
                                                 1.0f, 1.0f, 0);
      tin = tout;
      tout = (tout == thA) ? thB : thA;
    }
    // final sweep: gather fp16, combine with f32 x, write f32
    sweep64h<<<(NN + 7) / 8, 256, 0, stream>>>(tin, nullptr, (const float4*)xcur, nullptr,
                                               (float4*)tA, rowptr, meta4, coef, AL[l], 1);
    dense64<<<(NN + DN - 1) / DN, 256, 0, stream>>>(tA, Wl[l], bl[l], xcur, xcur,
                                                    (l < 4) ? xh : nullptr, 1, (l >= 2) ? 1 : 0);
  }
  // final projection y = x @ Wm.T + bm  -> tA
  dense64<<<(NN + DN - 1) / DN, 256, 0, stream>>>(xcur, Wm, bm, nullptr, tA, nullptr, 0, 0);
  score_k<<<(NN + 3) / 4, 256, 0, stream>>>(tA, wp, scores);
  topk_p1<<<P1B, 64, 0, stream>>>(scores, candv, candi);
  topk_p2_final<<<1, 64, 0, stream>>>(candv, candi, tA, out);
}